// Round 1
// baseline (3486.630 us; speedup 1.0000x reference)
//
#include <hip/hip_runtime.h>

#define NN 50000
#define EE 800000
#define DD 256
#define CC 4
#define BN_EPSF 1e-5f

typedef float v4f __attribute__((ext_vector_type(4)));

// ---------------- CSR build ----------------

__global__ void k_hist(const int* __restrict__ dst, int* __restrict__ cnt) {
  int e = blockIdx.x * 256 + threadIdx.x;
  if (e < EE) atomicAdd(&cnt[dst[e]], 1);
}

// single-block exclusive scan of cnt[0..NN) -> rp[0..NN], and cnt[i] := exclusive (cursor init)
__global__ void k_scan(int* __restrict__ cnt, int* __restrict__ rp) {
  __shared__ int wsums[16];
  __shared__ int sh_carry;
  __shared__ int sh_ctot;
  const int t = threadIdx.x;
  const int lane = t & 63;
  const int w = t >> 6;
  if (t == 0) sh_carry = 0;
  __syncthreads();
  for (int base = 0; base < NN; base += 1024) {
    int i = base + t;
    int v = (i < NN) ? cnt[i] : 0;
    int incl = v;
#pragma unroll
    for (int off = 1; off < 64; off <<= 1) {
      int u = __shfl_up(incl, off, 64);
      if (lane >= off) incl += u;
    }
    if (lane == 63) wsums[w] = incl;
    int cbase = sh_carry;
    __syncthreads();
    if (w == 0) {
      int s = (lane < 16) ? wsums[lane] : 0;
      int si = s;
#pragma unroll
      for (int off = 1; off < 16; off <<= 1) {
        int u = __shfl_up(si, off, 64);
        if (lane >= off) si += u;
      }
      if (lane < 16) wsums[lane] = si - s;  // exclusive wave offset
      if (lane == 15) sh_ctot = si;         // chunk total
    }
    __syncthreads();
    int excl = cbase + wsums[w] + (incl - v);
    if (i < NN) { rp[i] = excl; cnt[i] = excl; }
    __syncthreads();
    if (t == 0) sh_carry = cbase + sh_ctot;
    __syncthreads();
  }
  if (t == 0) rp[NN] = sh_carry;
}

__global__ void k_scatter(const int* __restrict__ src, const int* __restrict__ dst,
                          int* __restrict__ cur, int* __restrict__ ss, int* __restrict__ se) {
  int e = blockIdx.x * 256 + threadIdx.x;
  if (e < EE) {
    int d = dst[e];
    int p = atomicAdd(&cur[d], 1);
    ss[p] = src[e];
    se[p] = e;
  }
}

// ---------------- per-cluster kernels ----------------

// One wave per node: aggr[i] = sum over in-edges of relu(x[src] + edge_attr[e])
__global__ __launch_bounds__(256) void k_aggregate(
    const float* __restrict__ x, const float* __restrict__ ea,
    const int* __restrict__ rp, const int* __restrict__ ss,
    const int* __restrict__ se, float* __restrict__ aggr) {
  int node = (blockIdx.x * 256 + threadIdx.x) >> 6;
  int lane = threadIdx.x & 63;
  if (node >= NN) return;
  int beg = rp[node];
  int end = rp[node + 1];
  v4f acc = {0.f, 0.f, 0.f, 0.f};
  for (int p = beg; p < end; ++p) {
    int s = ss[p];
    int e = se[p];
    v4f xs = ((const v4f*)(x + (size_t)s * DD))[lane];
    v4f ev = __builtin_nontemporal_load(((const v4f*)(ea + (size_t)e * DD)) + lane);
    v4f sm = xs + ev;
    sm.x = fmaxf(sm.x, 0.f);
    sm.y = fmaxf(sm.y, 0.f);
    sm.z = fmaxf(sm.z, 0.f);
    sm.w = fmaxf(sm.w, 0.f);
    acc += sm;
  }
  ((v4f*)(aggr + (size_t)node * DD))[lane] = acc;
}

// GEMM sub-step: acc[4][8] = bias + zt(32x256 in LDS, row-major pad 264) @ Wg(256x256 row-major)
__device__ __forceinline__ void gemm_step(
    const float* __restrict__ Wg, const float* __restrict__ bg,
    float (&zt)[32][264], float (&wbuf)[32][256],
    float (&acc)[4][8], int t, int tc, int tr) {
#pragma unroll
  for (int j = 0; j < 8; ++j) {
    float bv = bg[tc + 32 * j];
#pragma unroll
    for (int i = 0; i < 4; ++i) acc[i][j] = bv;
  }
  for (int kc = 0; kc < 8; ++kc) {
    __syncthreads();  // protect wbuf reuse (and covers zt staging on kc==0)
#pragma unroll
    for (int j = 0; j < 8; ++j) {
      int idx = t + j * 256;
      int k = idx >> 6;
      int c4 = (idx & 63) * 4;
      *(float4*)&wbuf[k][c4] = *(const float4*)(Wg + (size_t)(kc * 32 + k) * DD + c4);
    }
    __syncthreads();
#pragma unroll
    for (int k4 = 0; k4 < 32; k4 += 4) {
      float4 zv[4];
#pragma unroll
      for (int i = 0; i < 4; ++i)
        zv[i] = *(const float4*)&zt[4 * tr + i][kc * 32 + k4];
#pragma unroll
      for (int kk = 0; kk < 4; ++kk) {
        float wv[8];
#pragma unroll
        for (int j = 0; j < 8; ++j) wv[j] = wbuf[k4 + kk][tc + 32 * j];
#pragma unroll
        for (int i = 0; i < 4; ++i) {
          float zs = (kk == 0) ? zv[i].x : (kk == 1) ? zv[i].y : (kk == 2) ? zv[i].z : zv[i].w;
#pragma unroll
          for (int j = 0; j < 8; ++j) acc[i][j] = fmaf(zs, wv[j], acc[i][j]);
        }
      }
    }
  }
}

// Fused: z=(1+eps)x+aggr; t=relu(z@W1+b1); h=t@W2+b2; y=mask*h+x; BN partial sums.
// y may alias aggr (same rows only within a block; ordered by barriers).
__global__ __launch_bounds__(256, 2) void k_mlp(
    const float* __restrict__ x, const float* aggr, float* y,
    const float* __restrict__ W1g, const float* __restrict__ b1g,
    const float* __restrict__ W2g, const float* __restrict__ b2g,
    const float* __restrict__ maskc, const float* __restrict__ epsp,
    float* __restrict__ gsum, float* __restrict__ gsumsq) {
  __shared__ __align__(16) float zt[32][264];
  __shared__ __align__(16) float wbuf[32][256];
  __shared__ float ssum[256];
  __shared__ float ssq[256];
  const int t = threadIdx.x;
  const int tc = t & 31;
  const int tr = t >> 5;
  const int row0 = blockIdx.x * 32;
  ssum[t] = 0.f;
  ssq[t] = 0.f;
  const float ep = 1.0f + epsp[0];
  // stage z (row-major, padded) -- coalesced float4 loads, conflict-free b128 stores
#pragma unroll
  for (int j = 0; j < 8; ++j) {
    int idx = t + j * 256;
    int r = idx >> 6;
    int c4 = (idx & 63) * 4;
    int row = row0 + r;
    float4 zv = make_float4(0.f, 0.f, 0.f, 0.f);
    if (row < NN) {
      float4 xv = *(const float4*)(x + (size_t)row * DD + c4);
      float4 av = *(const float4*)(aggr + (size_t)row * DD + c4);
      zv.x = fmaf(ep, xv.x, av.x);
      zv.y = fmaf(ep, xv.y, av.y);
      zv.z = fmaf(ep, xv.z, av.z);
      zv.w = fmaf(ep, xv.w, av.w);
    }
    *(float4*)&zt[r][c4] = zv;
  }
  float acc[4][8];
  gemm_step(W1g, b1g, zt, wbuf, acc, t, tc, tr);  // barrier at top covers staging
  __syncthreads();  // all zt reads of GEMM1 done
#pragma unroll
  for (int i = 0; i < 4; ++i)
#pragma unroll
    for (int j = 0; j < 8; ++j)
      zt[4 * tr + i][tc + 32 * j] = fmaxf(acc[i][j], 0.f);  // t = relu(.)
  float acc2[4][8];
  gemm_step(W2g, b2g, zt, wbuf, acc2, t, tc, tr);  // barrier at top covers t staging
  // epilogue: y = mask*h + x, BN partial sums (only valid rows)
  float ps[8], pq[8];
#pragma unroll
  for (int j = 0; j < 8; ++j) { ps[j] = 0.f; pq[j] = 0.f; }
#pragma unroll
  for (int i = 0; i < 4; ++i) {
    int row = row0 + 4 * tr + i;
    if (row < NN) {
      float m = maskc[row];
#pragma unroll
      for (int j = 0; j < 8; ++j) {
        int col = tc + 32 * j;
        float yv = fmaf(m, acc2[i][j], x[(size_t)row * DD + col]);
        y[(size_t)row * DD + col] = yv;
        ps[j] += yv;
        pq[j] += yv * yv;
      }
    }
  }
#pragma unroll
  for (int j = 0; j < 8; ++j) {
    atomicAdd(&ssum[tc + 32 * j], ps[j]);
    atomicAdd(&ssq[tc + 32 * j], pq[j]);
  }
  __syncthreads();
  atomicAdd(&gsum[t], ssum[t]);
  atomicAdd(&gsumsq[t], ssq[t]);
}

__global__ void k_bnstats(const float* __restrict__ gsum, const float* __restrict__ gsumsq,
                          const float* __restrict__ gamma_c, const float* __restrict__ beta_c,
                          float* __restrict__ scale, float* __restrict__ shift) {
  int d = threadIdx.x;
  const float inv_n = 1.0f / (float)NN;
  float mean = gsum[d] * inv_n;
  float var = fmaxf(gsumsq[d] * inv_n - mean * mean, 0.f);
  float sc = gamma_c[d] * rsqrtf(var + BN_EPSF);
  scale[d] = sc;
  shift[d] = fmaf(-mean, sc, beta_c[d]);
}

__global__ __launch_bounds__(256) void k_norm(
    const float* __restrict__ y, const float* __restrict__ scale,
    const float* __restrict__ shift, float* __restrict__ xout) {
  int idx = blockIdx.x * 256 + threadIdx.x;  // float4 index; grid covers exactly NN*DD/4
  int c4 = idx & 63;
  float4 yv = ((const float4*)y)[idx];
  float4 sc = ((const float4*)scale)[c4];
  float4 sh = ((const float4*)shift)[c4];
  float4 o;
  o.x = fmaf(sc.x, yv.x, sh.x);
  o.y = fmaf(sc.y, yv.y, sh.y);
  o.z = fmaf(sc.z, yv.z, sh.z);
  o.w = fmaf(sc.w, yv.w, sh.w);
  ((float4*)xout)[idx] = o;
}

__global__ __launch_bounds__(256) void k_norm_final(
    const float* __restrict__ y, const float* __restrict__ scale,
    const float* __restrict__ shift, const float* __restrict__ x_in,
    float* __restrict__ out) {
  int idx = blockIdx.x * 256 + threadIdx.x;
  int c4 = idx & 63;
  float4 yv = ((const float4*)y)[idx];
  float4 sc = ((const float4*)scale)[c4];
  float4 sh = ((const float4*)shift)[c4];
  float4 xi = ((const float4*)x_in)[idx];
  float4 o;
  o.x = xi.x + fmaxf(fmaf(sc.x, yv.x, sh.x), 0.f);
  o.y = xi.y + fmaxf(fmaf(sc.y, yv.y, sh.y), 0.f);
  o.z = xi.z + fmaxf(fmaf(sc.z, yv.z, sh.z), 0.f);
  o.w = xi.w + fmaxf(fmaf(sc.w, yv.w, sh.w), 0.f);
  ((float4*)out)[idx] = o;
}

// ---------------- launch ----------------

extern "C" void kernel_launch(void* const* d_in, const int* in_sizes, int n_in,
                              void* d_out, int out_size, void* d_ws, size_t ws_size,
                              hipStream_t stream) {
  (void)in_sizes; (void)n_in; (void)out_size; (void)ws_size;
  const float* x_in  = (const float*)d_in[0];
  const int*   ei    = (const int*)d_in[1];
  const float* ea    = (const float*)d_in[2];
  const float* masks = (const float*)d_in[3];
  // d_in[4] = complement_masks: unused by the reference
  const float* W1    = (const float*)d_in[5];
  const float* b1    = (const float*)d_in[6];
  const float* W2    = (const float*)d_in[7];
  const float* b2    = (const float*)d_in[8];
  const float* eps   = (const float*)d_in[9];
  const float* gamma = (const float*)d_in[10];
  const float* beta  = (const float*)d_in[11];
  float* out = (float*)d_out;

  // workspace layout (floats/ints, all 16B-aligned offsets); total ~110 MB
  float* x_cur = (float*)d_ws;                       // NN*DD
  float* yag   = x_cur + (size_t)NN * DD;            // NN*DD (aggr, then y)
  int*   ss    = (int*)(yag + (size_t)NN * DD);      // EE
  int*   se    = ss + EE;                            // EE
  int*   rp    = se + EE;                            // NN+1 (padded to 50016)
  int*   cnt   = rp + 50016;                         // NN (padded to 50016), also cursor
  float* gsum  = (float*)(cnt + 50016);              // CC*DD
  float* gsumsq = gsum + CC * DD;                    // CC*DD
  float* scale = gsumsq + CC * DD;                   // DD
  float* shift = scale + DD;                         // DD

  const int* src = ei;
  const int* dst = ei + EE;

  hipMemsetAsync(cnt, 0, NN * sizeof(int), stream);
  hipMemsetAsync(gsum, 0, 2 * CC * DD * sizeof(float), stream);

  k_hist<<<EE / 256, 256, 0, stream>>>(dst, cnt);
  k_scan<<<1, 1024, 0, stream>>>(cnt, rp);
  k_scatter<<<EE / 256, 256, 0, stream>>>(src, dst, cnt, ss, se);

  for (int c = 0; c < CC; ++c) {
    const float* xc = (c == 0) ? x_in : x_cur;
    k_aggregate<<<(NN + 3) / 4, 256, 0, stream>>>(xc, ea, rp, ss, se, yag);
    k_mlp<<<(NN + 31) / 32, 256, 0, stream>>>(
        xc, yag, yag,
        W1 + (size_t)c * DD * DD, b1 + (size_t)c * DD,
        W2 + (size_t)c * DD * DD, b2 + (size_t)c * DD,
        masks + (size_t)c * NN, eps + c,
        gsum + c * DD, gsumsq + c * DD);
    k_bnstats<<<1, DD, 0, stream>>>(gsum + c * DD, gsumsq + c * DD,
                                    gamma + (size_t)c * DD, beta + (size_t)c * DD,
                                    scale, shift);
    if (c < CC - 1)
      k_norm<<<(NN * DD / 4) / 256, 256, 0, stream>>>(yag, scale, shift, x_cur);
    else
      k_norm_final<<<(NN * DD / 4) / 256, 256, 0, stream>>>(yag, scale, shift, x_in, out);
  }
}